// Round 12
// baseline (253.820 us; speedup 1.0000x reference)
//
#include <hip/hip_runtime.h>

typedef unsigned short u16;
typedef unsigned int u32;
typedef __bf16 bf16x8 __attribute__((ext_vector_type(8)));
typedef float f32x4 __attribute__((ext_vector_type(4)));
typedef float f32x16 __attribute__((ext_vector_type(16)));
typedef u32 u32x4 __attribute__((ext_vector_type(4)));
typedef u32 u32x2 __attribute__((ext_vector_type(2)));

#define B_ 4
#define T_ 4096
#define D_ 1024
#define H_ 1024
#define M_ 16384   // B*T
#define N_ 2048    // 2H
#define K_ 1024
#define CHANS 4096 // B*H
#define CHUNKS 64
#define CLEN 64    // T / CHUNKS

#define BM 256
#define BN 256
#define BK 64
#define NT2 (K_ / (2 * BK)) // 8 double-K-tile iterations

__device__ __forceinline__ u16 f2b(float f) {
    unsigned u = __float_as_uint(f);
    unsigned r = (u + 0x7FFFu + ((u >> 16) & 1u)) >> 16;
    return (u16)r;
}
__device__ __forceinline__ float b2f(u32 v) {
    return __uint_as_float(v << 16);
}
__device__ __forceinline__ float sigm(float x) { return 1.f / (1.f + __expf(-x)); }

#define GLDS16(gp, lp)                                                         \
    __builtin_amdgcn_global_load_lds(                                          \
        (__attribute__((address_space(1))) void*)(gp),                         \
        (__attribute__((address_space(3))) void*)(lp), 16, 0, 0)

#define BAR() __builtin_amdgcn_s_barrier()
#define LGKM0() asm volatile("s_waitcnt lgkmcnt(0)" ::: "memory")
#define WAITVM(N) asm volatile("s_waitcnt vmcnt(" #N ")" ::: "memory")

// ---------------- convert x: fp32 -> bf16 ----------------
__global__ __launch_bounds__(256) void cvt_x(const float* __restrict__ in,
                                             u16* __restrict__ out, int n8) {
    int i = blockIdx.x * 256 + threadIdx.x;
    int stride = gridDim.x * 256;
    for (; i < n8; i += stride) {
        const f32x4* p = (const f32x4*)(in + (size_t)i * 8);
        f32x4 v0 = __builtin_nontemporal_load(p);
        f32x4 v1 = __builtin_nontemporal_load(p + 1);
        u16 o[8];
        o[0] = f2b(v0.x); o[1] = f2b(v0.y); o[2] = f2b(v0.z); o[3] = f2b(v0.w);
        o[4] = f2b(v1.x); o[5] = f2b(v1.y); o[6] = f2b(v1.z); o[7] = f2b(v1.w);
        *(uint4*)(out + (size_t)i * 8) = *(const uint4*)o;
    }
}

// ---------------- transpose + permute + convert W -> Wt [N][K] bf16 ----------
// permuted col c: tau=c>>5, w=c&31 -> orig col (tau&1)*1024 + (tau>>1)*32 + w
// (32-col tile pairs: even tile = gates for h-group, odd tile = values)
__global__ __launch_bounds__(256) void tr_w(const float* __restrict__ W0,
                                            const float* __restrict__ W1,
                                            u16* __restrict__ Wt) {
    __shared__ float tile[32][33];
    const float* W = blockIdx.z ? W1 : W0;
    u16* Wo = Wt + (size_t)blockIdx.z * N_ * K_;
    int kt = blockIdx.x * 32;
    int nt = blockIdx.y * 32;
    int tx = threadIdx.x & 31;
    int ty = threadIdx.x >> 5;
    int tau = nt >> 5;
    int oc = (tau & 1) * 1024 + (tau >> 1) * 32 + tx;
#pragma unroll
    for (int i = 0; i < 4; ++i)
        tile[ty + i * 8][tx] = W[(size_t)(kt + ty + i * 8) * N_ + oc];
    __syncthreads();
#pragma unroll
    for (int i = 0; i < 4; ++i)
        Wo[(size_t)(nt + ty + i * 8) * K_ + kt + tx] = f2b(tile[tx][ty + i * 8]);
}

// ---- 256x256 8-wave GEMM with 32x32x16 MFMA, race-free 4-phase schedule ----
// LDS 128KB: [A buf0 32K][A buf1 32K][B buf0 32K][B buf1 32K]
// Staging invariant: a buffer is staged only in a phase strictly after its
// last-read phase (buf1 staged at P1, read P3/P4; buf0 staged at P3, read
// next P1/P2) -- never a same-phase read/write overlap (R11's race).
__global__ __launch_bounds__(512, 2) void gemm_fused(const u16* __restrict__ A,
                                                     const u16* __restrict__ Bt,
                                                     const float* __restrict__ bias,
                                                     u32* __restrict__ GI,
                                                     float* __restrict__ Aagg,
                                                     float* __restrict__ Uagg) {
    __shared__ u16 lds[65536];

    const int tid = threadIdx.x;
    const int w = tid >> 6;
    const int l = tid & 63;
    const int wm = w >> 2; // 0..1 (M half, 128 rows)
    const int wn = w & 3;  // 0..3 (N quarter, 64 cols)

    int swz = (blockIdx.x & 7) * 64 + (blockIdx.x >> 3);
    const int brow = (swz >> 3) * BM;
    const int bcol = (swz & 7) * BN;

    // ---- staging: linear LDS dest, granule-XOR pre-swizzled source ----
    const int arow = tid >> 3; // 0..63
    const int aq8 = (((tid & 7) ^ (arow & 7)) << 3);
    const int tid8 = tid * 8;
    const u16* aSrc = A + (size_t)(brow + arow) * K_ + aq8;
    const u16* bSrc = Bt + (size_t)(bcol + arow) * K_ + aq8;

#define STG_A(d, h, k0)                                                        \
    do {                                                                       \
        GLDS16(aSrc + (size_t)((h)*128) * K_ + (k0),                           \
               &lds[(d)*16384 + (h)*8192 + tid8]);                             \
        GLDS16(aSrc + (size_t)((h)*128 + 64) * K_ + (k0),                      \
               &lds[(d)*16384 + (h)*8192 + 4096 + tid8]);                      \
    } while (0)
#define STG_B(d, h, k0)                                                        \
    do {                                                                       \
        GLDS16(bSrc + (size_t)((h)*128) * K_ + (k0),                           \
               &lds[32768 + (d)*16384 + (h)*8192 + tid8]);                     \
        GLDS16(bSrc + (size_t)((h)*128 + 64) * K_ + (k0),                      \
               &lds[32768 + (d)*16384 + (h)*8192 + 4096 + tid8]);              \
    } while (0)

    // ---- read-side fragment addressing (32x32x16 layout) ----
    // A operand: lane holds row = l&31, k-half hi = l>>5 (8 contiguous bf16)
    // LDS granule for k-slice s: g = 2s + hi, swizzled g ^ (row&7) = g ^ (l&7)
    const int lc = l & 31, hi = l >> 5, l7 = l & 7;
    int gs[4];
#pragma unroll
    for (int s = 0; s < 4; ++s) gs[s] = ((2 * s + hi) ^ l7) << 3;
    const int rowA = (wm * 128 + lc) * 64;        // u16 idx base (A)
    const int rowB = 32768 + (wn * 64 + lc) * 64; // u16 idx base (B)

    f32x16 acc[4][2];
#pragma unroll
    for (int m = 0; m < 4; ++m)
#pragma unroll
        for (int n = 0; n < 2; ++n)
#pragma unroll
            for (int e = 0; e < 16; ++e) acc[m][n][e] = 0.f;

#define RD2(afr, bfr, off, s0)                                                 \
    _Pragma("unroll") for (int si = 0; si < 2; ++si) {                         \
        _Pragma("unroll") for (int m = 0; m < 4; ++m)                          \
            afr[m][si] = *(const bf16x8*)&lds[(off) + rowA + m * 2048 +        \
                                              gs[(s0) + si]];                  \
        _Pragma("unroll") for (int n = 0; n < 2; ++n)                          \
            bfr[n][si] = *(const bf16x8*)&lds[(off) + rowB + n * 2048 +        \
                                              gs[(s0) + si]];                  \
    }
#define MFMA16(afr, bfr)                                                       \
    __builtin_amdgcn_s_setprio(1);                                             \
    _Pragma("unroll") for (int si = 0; si < 2; ++si)                           \
        _Pragma("unroll") for (int m = 0; m < 4; ++m)                          \
            _Pragma("unroll") for (int n = 0; n < 2; ++n)                      \
                acc[m][n] = __builtin_amdgcn_mfma_f32_32x32x16_bf16(           \
                    afr[m][si], bfr[n][si], acc[m][n], 0, 0, 0);               \
    __builtin_amdgcn_s_setprio(0);

    // prologue: tile 0 -> buf0 only
    STG_A(0, 0, 0); STG_A(0, 1, 0); STG_B(0, 0, 0); STG_B(0, 1, 0);
    WAITVM(0);
    BAR();

#pragma unroll 1
    for (int j = 0; j < NT2; ++j) {
        const int k1 = j * 2 * BK + BK; // tile 2j+1 -> buf1
        const int k2 = k1 + BK;         // tile 2j+2 -> buf0
        const bool pf = (j + 1 < NT2);
        bf16x8 af[4][2], bf[2][2];

        // ---- P1: buf0 slices 0-1; stage ALL of buf1 (tile 2j+1) ----
        // (buf1 last read at prev P4, LGKM0+BAR separated -> race-free)
        RD2(af, bf, 0, 0);
        STG_A(1, 0, k1); STG_A(1, 1, k1);
        STG_B(1, 0, k1); STG_B(1, 1, k1);
        BAR(); LGKM0();
        MFMA16(af, bf);
        BAR();
        // ---- P2: buf0 slices 2-3; drain buf1 loads before P3 reads ----
        RD2(af, bf, 0, 2);
        BAR(); LGKM0();
        MFMA16(af, bf);
        WAITVM(0);
        BAR();
        // ---- P3: buf1 slices 0-1; stage ALL of buf0 (tile 2j+2) ----
        // (buf0 last read at P2, LGKM0+BAR separated -> race-free)
        RD2(af, bf, 16384, 0);
        if (pf) {
            STG_A(0, 0, k2); STG_A(0, 1, k2);
            STG_B(0, 0, k2); STG_B(0, 1, k2);
        }
        BAR(); LGKM0();
        MFMA16(af, bf);
        BAR();
        // ---- P4: buf1 slices 2-3; drain buf0 loads before next P1 ----
        RD2(af, bf, 16384, 2);
        BAR(); LGKM0();
        MFMA16(af, bf);
        WAITVM(0);
        BAR();
    }

    // ---- fused epilogue (32x32 C/D layout: col=l&31, row=(r&3)+8(r>>2)+4hi)
    // acc[m][0] = gates, acc[m][1] = values for SAME h = h0 + lc (in-lane).
    const int h = ((bcol + wn * 64) >> 6) * 32 + lc;
    const float bg = bias[h];
    const float bv = bias[H_ + h];
    float aCh[2] = {1.f, 1.f}, uCh[2] = {0.f, 0.f};
#pragma unroll
    for (int m = 0; m < 4; ++m) {
        const int rb = brow + wm * 128 + m * 32;
        float amt = 1.f, umt = 0.f;
#pragma unroll
        for (int q = 0; q < 4; ++q) {
            float aq = 1.f, uq = 0.f;
#pragma unroll
            for (int jj = 0; jj < 4; ++jj) {
                float pg = acc[m][0][q * 4 + jj] + bg;
                float pv = acc[m][1][q * 4 + jj] + bv;
                float g = sigm(pg);
                float in = (1.f - g) * pv;
                u32 gq = __float2uint_rn(g * 65535.f);
                GI[(size_t)(rb + q * 8 + hi * 4 + jj) * H_ + h] =
                    ((u32)f2b(in) << 16) | gq;
                uq = uq * g + in; // jj ascending (rows consecutive)
                aq *= g;
            }
            // ordered cross-hi compose of rows [q*8, q*8+8): hi=0 early
            float pa = __shfl_xor(aq, 32), pu = __shfl_xor(uq, 32);
            float a8, u8;
            if (hi) { a8 = pa * aq; u8 = pu * aq + uq; }
            else    { a8 = aq * pa; u8 = uq * pa + pu; }
            umt = umt * a8 + u8; // q ascending
            amt = amt * a8;
        }
        const int ch = m >> 1;
        uCh[ch] = uCh[ch] * amt + umt; // m ascending within chunk
        aCh[ch] = aCh[ch] * amt;
    }
    if (hi == 0) {
        int R = brow + wm * 128;
        int bidx = R >> 12;     // batch
        int t0 = (R >> 6) & 63; // first chunk index (even)
        int chan = bidx * 1024 + h;
#pragma unroll
        for (int ch = 0; ch < 2; ++ch) {
            Aagg[(size_t)(t0 + ch) * CHANS + chan] = aCh[ch];
            Uagg[(size_t)(t0 + ch) * CHANS + chan] = uCh[ch];
        }
    }
}

// ---------------- scan pass B: scan chunk aggregates ----------------
__global__ __launch_bounds__(256) void scan_passB(const float* __restrict__ Aagg,
                                                  const float* __restrict__ Uagg,
                                                  const float* __restrict__ state_in,
                                                  float* __restrict__ chunkH0,
                                                  float* __restrict__ state_out) {
    int chan = blockIdx.x * 256 + threadIdx.x;
    float h = state_in[chan];
#pragma unroll 8
    for (int c = 0; c < CHUNKS; ++c) {
        chunkH0[(size_t)c * CHANS + chan] = h;
        h = Aagg[(size_t)c * CHANS + chan] * h + Uagg[(size_t)c * CHANS + chan];
    }
    state_out[chan] = h;
}

// ------- scan pass C: replay chunk, 4 channels/thread, prefetched -------
template <int OUT_BF16>
__global__ __launch_bounds__(256) void scan_passC(const u32* __restrict__ GI,
                                                  const float* __restrict__ chunkH0,
                                                  void* __restrict__ outp) {
    int i = blockIdx.x * 256 + threadIdx.x; // [0, 65536)
    int grp = i & 1023;  // (batch, 4-chan group)
    int chunk = i >> 10; // 0..63
    int b = grp >> 8, g = grp & 255;
    int chan = b * 1024 + g * 4; // channel index for chunkH0 (batch-major)
    size_t row0 = (size_t)b * T_ + (size_t)chunk * CLEN;
    const u32x4* p = (const u32x4*)GI + row0 * (H_ / 4) + g;
    f32x4 hv = *(const f32x4*)&chunkH0[(size_t)chunk * CHANS + chan];
    const float inv = 1.f / 65535.f;
    u32x4 v = __builtin_nontemporal_load(p);
#pragma unroll 4
    for (int t = 0; t < CLEN; ++t) {
        u32x4 vn;
        if (t + 1 < CLEN)
            vn = __builtin_nontemporal_load(p + (size_t)(t + 1) * (H_ / 4));
        hv.x = (float)(v.x & 0xffffu) * inv * hv.x + b2f(v.x >> 16);
        hv.y = (float)(v.y & 0xffffu) * inv * hv.y + b2f(v.y >> 16);
        hv.z = (float)(v.z & 0xffffu) * inv * hv.z + b2f(v.z >> 16);
        hv.w = (float)(v.w & 0xffffu) * inv * hv.w + b2f(v.w >> 16);
        size_t o = (row0 + t) * H_ + g * 4; // column = g*4 (batch lives in row)
        if (OUT_BF16) {
            u32x2 pk;
            pk.x = (u32)f2b(hv.x) | ((u32)f2b(hv.y) << 16);
            pk.y = (u32)f2b(hv.z) | ((u32)f2b(hv.w) << 16);
            *(u32x2*)&((u16*)outp)[o] = pk;
        } else {
            __builtin_nontemporal_store(hv, (f32x4*)&((float*)outp)[o]);
        }
        v = vn;
    }
}

extern "C" void kernel_launch(void* const* d_in, const int* in_sizes, int n_in,
                              void* d_out, int out_size, void* d_ws, size_t ws_size,
                              hipStream_t stream) {
    const float* x = (const float*)d_in[0];
    const float* W0 = (const float*)d_in[1];
    const float* b0 = (const float*)d_in[2];
    const float* W1 = (const float*)d_in[3];
    const float* b1 = (const float*)d_in[4];
    const float* state = (const float*)d_in[5];
    float* out = (float*)d_out;

    char* ws = (char*)d_ws;
    u16* xb = (u16*)ws;                     // 33,554,432 B
    u16* h1b = (u16*)(ws + 33554432);       // 33,554,432 B
    u16* Wt = (u16*)(ws + 67108864);        // 8,388,608 B
    u32* GIb = (u32*)(ws + 75497472);       // 67,108,864 B
    float* Aagg = (float*)(ws + 142606336); // 1,048,576 B
    float* Uagg = (float*)(ws + 143654912); // 1,048,576 B
    float* cH0 = (float*)(ws + 144703488);  // 1,048,576 B

    cvt_x<<<2048, 256, 0, stream>>>(x, xb, M_ * K_ / 8);
    tr_w<<<dim3(32, 64, 2), 256, 0, stream>>>(W0, W1, Wt);

    for (int l = 0; l < 2; ++l) {
        const u16* Aop = l ? h1b : xb;
        const float* bias = l ? b1 : b0;
        gemm_fused<<<(M_ / BM) * (N_ / BN), 512, 0, stream>>>(
            Aop, Wt + (size_t)l * N_ * K_, bias, GIb, Aagg, Uagg);
        scan_passB<<<CHANS / 256, 256, 0, stream>>>(
            Aagg, Uagg, state + (size_t)l * CHANS, cH0,
            out + (size_t)M_ * H_ + (size_t)l * CHANS);
        if (l == 0)
            scan_passC<1><<<256, 256, 0, stream>>>(GIb, cH0, h1b);
        else
            scan_passC<0><<<256, 256, 0, stream>>>(GIb, cH0, out);
    }
}